// Round 8
// baseline (57.496 us; speedup 1.0000x reference)
//
#include <hip/hip_runtime.h>

#define D 32
#define H 128
#define TN 256            // tanh table entries
#define TRANGE 6.0f       // table covers [-6, 6]

typedef float v2f __attribute__((ext_vector_type(2)));

// ---------------- Stage A: metric + folded per-batch constants ----------------
// grid = 256: blk = (b, q); q = m-chunk of 128 metric outputs. h1 recomputed
// redundantly per block. cpk4 holds table-index-space constants:
// u = S*x + TN/2 = (S*cbase + 128) + (S*a1)gij + (S*a2)gjk + (S*a3)gki
__global__ __launch_bounds__(256) void setup_kernel(
    const float* __restrict__ points,
    const float* __restrict__ mw1, const float* __restrict__ mb1,
    const float* __restrict__ mw2, const float* __restrict__ mb2,
    const float* __restrict__ cw1, const float* __restrict__ cb1,
    const float* __restrict__ rw1, const float* __restrict__ rb1,
    float* __restrict__ metric, float4* __restrict__ cpk4,
    float* __restrict__ rbase)
{
    __shared__ float p[D];
    __shared__ float h1[H];
    const int blk = blockIdx.x;
    const int b   = blk >> 3;
    const int q   = blk & 7;
    const int t   = threadIdx.x;
    if (t < D) p[t] = points[b * D + t];
    __syncthreads();

    if (t < H) {
        float acc = mb1[t];
        #pragma unroll
        for (int d = 0; d < D; ++d) acc = fmaf(p[d], mw1[d * H + t], acc);
        h1[t] = fmaxf(acc, 0.0f);
    }

    if (q == 0 && t < H) {
        constexpr float S = (float)TN / (2.0f * TRANGE);   // 21.3333
        float cacc = cb1[t];
        #pragma unroll
        for (int d = 0; d < D; ++d) cacc = fmaf(p[d], cw1[d * H + t], cacc);
        cpk4[b * H + t] = make_float4(S * cacc + (float)(TN / 2),
                                      S * cw1[32 * H + t],
                                      S * cw1[33 * H + t],
                                      S * cw1[34 * H + t]);
    }
    if (q == 1) {
        float racc = rb1[t];
        #pragma unroll
        for (int d = 0; d < D; ++d) racc = fmaf(p[d], rw1[d * 256 + t], racc);
        rbase[b * 256 + t] = racc;
    }
    __syncthreads();

    if (t < 128) {
        const int m = q * 128 + t;
        float acc = mb2[m];
        #pragma unroll 8
        for (int h = 0; h < H; ++h) acc = fmaf(h1[h], mw2[h * 1024 + m], acc);
        metric[b * 1024 + m] = acc;
    }
}

// ---------------- Stage B: christoffel, 1M rows ----------------
// 128-thread blocks, 16 blocks/CU -> 32 waves/CU (2x R6 occupancy).
// 256-entry LDS interp table (2 KB, err ~2e-4); metric values loaded
// directly from L2 (5 one-time loads/thread, no LDS stage, no barrier wait).
// Per eval: 2 FMA (index-space u) + med3 + 2 cvt + sub + 1 ds_read_b64 +
// 2 FMA (interp, acc). Constants via wave-uniform s_load stream.
// grid = 32*32*4 = 4096 blocks (b, i, quarter of 256 rows), block = 128.
__global__ __launch_bounds__(128) void christoffel_kernel(
    const float* __restrict__ metric,
    const float4* __restrict__ cpk4, const float* __restrict__ cw2,
    const float* __restrict__ cb2,
    float* __restrict__ gamma)
{
    __shared__ float2 tab[TN];          // 2 KB: {tanh(x_i), tanh(x_{i+1})-tanh(x_i)}
    const int blk = blockIdx.x;
    const int b   = blk >> 7;
    const int i   = (blk >> 2) & 31;
    const int q   = blk & 3;
    const int t   = threadIdx.x;

    // one-time table fill: 2 entries per thread
    constexpr float hstep = 2.0f * TRANGE / (float)TN;
    constexpr float Kc = 2.8853900817779268f;   // 2*log2(e)
    #pragma unroll
    for (int e = 0; e < TN / 128; ++e) {
        const int idx = e * 128 + t;
        const float x0 = -TRANGE + idx * hstep;
        const float e0 = __builtin_amdgcn_exp2f(Kc * x0);
        const float v0 = 1.0f - 2.0f * __builtin_amdgcn_rcpf(e0 + 1.0f);
        const float e1 = __builtin_amdgcn_exp2f(Kc * (x0 + hstep));
        const float v1 = 1.0f - 2.0f * __builtin_amdgcn_rcpf(e1 + 1.0f);
        tab[idx] = make_float2(v0, v1 - v0);
    }

    // per-thread metric values straight from L2 (no LDS staging)
    const int r0 = q * 256 + t * 2;     // row within (b,i): r = j*32 + k
    const int j  = r0 >> 5;
    const int k0 = r0 & 31;             // even
    const float* __restrict__ Mb = metric + b * 1024;
    const float gij  = Mb[i * 32 + j];
    const float gjk0 = Mb[j * 32 + k0];
    const float gjk1 = Mb[j * 32 + k0 + 1];
    const float gki0 = Mb[k0 * 32 + i];
    const float gki1 = Mb[(k0 + 1) * 32 + i];
    __syncthreads();

    float acc0 = 0.0f, acc1 = 0.0f;
    const float4* __restrict__ cp = cpk4 + b * H;   // wave-uniform stream

    #pragma unroll 8
    for (int h = 0; h < H; ++h) {
        const float4 c = cp[h];         // s_load_dwordx4 (uniform)
        const float w = cw2[h];         // s_load_dword (uniform)
        const float pre = fmaf(gij, c.y, c.x);
        float u0 = fmaf(gki0, c.w, fmaf(gjk0, c.z, pre));
        float u1 = fmaf(gki1, c.w, fmaf(gjk1, c.z, pre));
        u0 = __builtin_amdgcn_fmed3f(u0, 0.0f, 255.0f);
        u1 = __builtin_amdgcn_fmed3f(u1, 0.0f, 255.0f);
        const int i0 = (int)u0;
        const int i1 = (int)u1;
        const float fr0 = u0 - (float)i0;
        const float fr1 = u1 - (float)i1;
        const float2 p0 = tab[i0];      // ds_read_b64
        const float2 p1 = tab[i1];
        acc0 = fmaf(fmaf(fr0, p0.y, p0.x), w, acc0);
        acc1 = fmaf(fmaf(fr1, p1.y, p1.x), w, acc1);
    }

    const float bias = cb2[0];
    v2f res; res.x = acc0 + bias; res.y = acc1 + bias;
    *((v2f*)(gamma + ((b * 32 + i) * 32 + j) * 32 + k0)) = res;
}

// ---------------- Stage C: ricci ----------------
// Block = (b,i,jhalf): 16 outputs. Thread = hidden unit h; 33 weights in VGPRs.
// Gamma rows wave-uniform -> scalar load stream. Paired shuffle reduction.
// grid = 2048, block = 256
__global__ __launch_bounds__(256) void ricci_kernel(
    const float* __restrict__ metric, const float* __restrict__ rbase,
    const float* __restrict__ rw1, const float* __restrict__ rw2,
    const float* __restrict__ rb2,
    const float* __restrict__ gamma,
    float* __restrict__ out)
{
    __shared__ float red[4][16];
    const int blk = blockIdx.x;
    const int bi  = blk >> 1;           // (b,i)
    const int b   = blk >> 6;
    const int i   = (blk >> 1) & 31;
    const int jh  = blk & 1;
    const int t   = threadIdx.x;

    float w[33];
    #pragma unroll
    for (int f = 0; f < 33; ++f) w[f] = rw1[(32 + f) * 256 + t];
    const float rbv   = rbase[b * 256 + t];
    const float wo    = rw2[t];
    const float rbias = rb2[0];

    const float4* __restrict__ G4   = (const float4*)(gamma + bi * 1024 + jh * 512);
    const float*  __restrict__ Mrow = metric + b * 1024 + i * 32 + jh * 16;

    const int wid  = t >> 6;
    const int lane = t & 63;

    #pragma unroll 2
    for (int jp = 0; jp < 8; ++jp) {
        float pp[2];
        #pragma unroll
        for (int s = 0; s < 2; ++s) {
            const int jj = jp * 2 + s;
            v2f hA = (v2f)(0.0f), hB = (v2f)(0.0f);
            #pragma unroll
            for (int k4 = 0; k4 < 8; ++k4) {
                const float4 g = G4[jj * 8 + k4];   // uniform -> scalar load
                v2f glo; glo.x = g.x; glo.y = g.y;
                v2f ghi; ghi.x = g.z; ghi.y = g.w;
                v2f wlo; wlo.x = w[k4 * 4 + 1]; wlo.y = w[k4 * 4 + 2];
                v2f whi; whi.x = w[k4 * 4 + 3]; whi.y = w[k4 * 4 + 4];
                hA = glo * wlo + hA;
                hB = ghi * whi + hB;
            }
            const float hid = fmaf(Mrow[jj], w[0], rbv) + (hA.x + hA.y) + (hB.x + hB.y);
            pp[s] = fmaxf(hid, 0.0f) * wo;
        }
        const float t0 = pp[0] + __shfl_xor(pp[0], 1);
        const float t1 = pp[1] + __shfl_xor(pp[1], 1);
        float z = (lane & 1) ? t1 : t0;
        #pragma unroll
        for (int off = 2; off < 64; off <<= 1) z += __shfl_xor(z, off);
        if (lane < 2) red[wid][jp * 2 + lane] = z;
    }
    __syncthreads();
    if (t < 16) out[bi * 32 + jh * 16 + t] = red[0][t] + red[1][t] + red[2][t] + red[3][t] + rbias;
}

extern "C" void kernel_launch(void* const* d_in, const int* in_sizes, int n_in,
                              void* d_out, int out_size, void* d_ws, size_t ws_size,
                              hipStream_t stream) {
    const float* points = (const float*)d_in[0];
    const float* mw1 = (const float*)d_in[1];
    const float* mb1 = (const float*)d_in[2];
    const float* mw2 = (const float*)d_in[3];
    const float* mb2 = (const float*)d_in[4];
    const float* cw1 = (const float*)d_in[5];
    const float* cb1 = (const float*)d_in[6];
    const float* cw2 = (const float*)d_in[7];
    const float* cb2 = (const float*)d_in[8];
    const float* rw1 = (const float*)d_in[9];
    const float* rb1 = (const float*)d_in[10];
    const float* rw2 = (const float*)d_in[11];
    const float* rb2 = (const float*)d_in[12];
    float* out = (float*)d_out;

    char* ws = (char*)d_ws;
    float*  metric = (float*)(ws);                 // 32*1024 f32 = 128 KB @ 0
    float4* cpk4   = (float4*)(ws + 131072);       // 32*128 float4 = 64 KB
    float*  rbase  = (float*)(ws + 196608);        // 32*256 f32 = 32 KB
    float*  gamma  = (float*)(ws + 262144);        // 32*32768 f32 = 4 MB

    setup_kernel<<<256, 256, 0, stream>>>(points, mw1, mb1, mw2, mb2,
                                          cw1, cb1, rw1, rb1,
                                          metric, cpk4, rbase);
    christoffel_kernel<<<4096, 128, 0, stream>>>(metric, cpk4, cw2, cb2, gamma);
    ricci_kernel<<<2048, 256, 0, stream>>>(metric, rbase, rw1, rw2, rb2, gamma, out);
}